// Round 8
// baseline (15.408 us; speedup 1.0000x reference)
//
#include <hip/hip_runtime.h>

#define EPSF 1e-8f
#define NCENT 16
#define NCHAN 128
#define NCELL 511          // cell = floor(2t)+256 for t in [-128,127] -> [0,510]
#define TOL   2e-4f        // boundary-nearness guard in t2-units (err bound 4.6e-5, 4x margin)
#define TOLT  1e-4f        // definite-saturation guard in t-units (err bound 2.8e-5)

typedef float f32x4 __attribute__((ext_vector_type(4)));

// Exact reference argmin: first-index tie-break (strict <), centers pre-rounded.
__device__ __forceinline__ float nearest_center(float t, const float* c) {
    float best = fabsf(t - c[0]);
    float q = c[0];
#pragma unroll
    for (int k = 1; k < NCENT; ++k) {
        float d = fabsf(t - c[k]);
        bool lt = d < best;
        best = lt ? d : best;
        q = lt ? c[k] : q;
    }
    return q;
}

// Bit-exact slow path: full IEEE divide (verified absmax==0 in R2-R7).
__device__ __forceinline__ float quant_exact(float xin, float sdv, float sml,
                                             const float* qlut) {
    float t = xin / sdv;                       // sdv = (scale+eps)/128, pow2-exact fold
    t = fminf(fmaxf(t, -128.0f), 127.0f);
    float t2 = t + t;
    float f = floorf(t2);
    int cell = (int)f + 256;
    int idx = (t2 == f) ? (cell + 512) : cell;
    return qlut[idx] * sml;
}

// Fast path: reciprocal multiply + exactness guard. Sets `slow` when the
// approx t2 is too close to an integer to trust cell/boundary assignment.
__device__ __forceinline__ float quant_fast(float xin, float rrec, float sml,
                                            const float* qlut, bool& slow) {
    float ta = xin * rrec;                     // |t2a - t2exact| <= ~4.6e-5
    float t = fminf(fmaxf(ta, -128.0f), 127.0f);
    float t2 = t + t;
    float f = floorf(t2);
    float d = t2 - f;                          // exact subtraction, in [0,1)
    int cell = (int)f + 256;
    int idx = (d == 0.0f) ? (cell + 512) : cell;
    bool near = (d < TOL) | (d > 1.0f - TOL);
    // definitely saturated: exact t also clips -> boundary LUT correct, keep fast
    bool defsat = (ta > 127.0f + TOLT) | (ta < -128.0f - TOLT);
    slow = near & !defsat;
    return qlut[idx] * sml;
}

// A/B vs R7: ONLY change is __launch_bounds__(256, 8) -> cap 64 VGPR for
// 8 waves/EU (32 waves/CU). R7's unrolled batch likely sat in the 65-128
// VGPR band (16 waves/CU), halving the latency-hiding pool.
__global__ __launch_bounds__(256, 8) void lut_fakequant_kernel(
    const float* __restrict__ x,
    const float* __restrict__ scale,
    const float* __restrict__ centers_g,
    float* __restrict__ out,
    int n4)
{
    __shared__ float srec[NCHAN];        // fl(1 / ((scale+eps)/128))
    __shared__ float sdiv[NCHAN];        // (scale+eps)/128  (exact pow2 scaling)
    __shared__ float smul[NCHAN];        // scale/128        (exact pow2 scaling)
    __shared__ float qlut[NCELL + 512];  // [0..510]=interior, [512..1022]=boundary

    const int base = blockIdx.x * blockDim.x + threadIdx.x;
    const int stride = gridDim.x * blockDim.x;
    const bool fastpath = (base + 3 * stride < n4);

    const f32x4* __restrict__ x4 = (const f32x4*)x;
    f32x4* __restrict__ out4 = (f32x4*)out;

    // Issue the x loads FIRST (cached: x is L3-resident across replays, R5).
    // Their latency covers the whole prologue (R7: -1.65 us).
    f32x4 v0, v1, v2, v3;
    if (fastpath) {
        v0 = x4[base];
        v1 = x4[base + stride];
        v2 = x4[base + 2 * stride];
        v3 = x4[base + 3 * stride];
    }

    // Prologue: scale/centers loads + LUT build, overlapped with x loads.
    if (threadIdx.x < NCHAN) {
        float s = scale[threadIdx.x];
        float dv = (s + EPSF) * 0.0078125f;
        sdiv[threadIdx.x] = dv;
        srec[threadIdx.x] = 1.0f / dv;
        smul[threadIdx.x] = s * 0.0078125f;
    }

    // Rounded codebook (uniform addr). jnp.round == round-half-even == rintf.
    float c[NCENT];
#pragma unroll
    for (int k = 0; k < NCENT; ++k) c[k] = rintf(centers_g[k]);

    // Piecewise-constant LUT built with the exact reference argmin.
    for (int u = threadIdx.x; u < NCELL; u += blockDim.x) {
        float tb = (float)(u - 256) * 0.5f;
        qlut[u]       = nearest_center(tb + 0.25f, c);  // interior of cell
        qlut[u + 512] = nearest_center(tb, c);          // exact-boundary (tie-break)
    }
    __syncthreads();

    if (fastpath) {
        const int c4 = base & (NCHAN / 4 - 1);   // stride%32==0 -> shared channel slot
        f32x4 rv = ((const f32x4*)srec)[c4];
        f32x4 mv = ((const f32x4*)smul)[c4];

        f32x4 vin[4] = {v0, v1, v2, v3};
        f32x4 ovec[4];
#pragma unroll
        for (int g = 0; g < 4; ++g) {
            bool s0, s1, s2, s3;
            f32x4 o;
            o[0] = quant_fast(vin[g][0], rv[0], mv[0], qlut, s0);
            o[1] = quant_fast(vin[g][1], rv[1], mv[1], qlut, s1);
            o[2] = quant_fast(vin[g][2], rv[2], mv[2], qlut, s2);
            o[3] = quant_fast(vin[g][3], rv[3], mv[3], qlut, s3);
            if (__builtin_expect(s0 | s1 | s2 | s3, 0)) {   // rare divergent redo
                f32x4 dv = ((const f32x4*)sdiv)[c4];
                if (s0) o[0] = quant_exact(vin[g][0], dv[0], mv[0], qlut);
                if (s1) o[1] = quant_exact(vin[g][1], dv[1], mv[1], qlut);
                if (s2) o[2] = quant_exact(vin[g][2], dv[2], mv[2], qlut);
                if (s3) o[3] = quant_exact(vin[g][3], dv[3], mv[3], qlut);
            }
            ovec[g] = o;
        }

        // nt stores: store-allocate thrashes the 32 MB aggregate L2 (R6: +2.2 us).
        __builtin_nontemporal_store(ovec[0], &out4[base]);
        __builtin_nontemporal_store(ovec[1], &out4[base + stride]);
        __builtin_nontemporal_store(ovec[2], &out4[base + 2 * stride]);
        __builtin_nontemporal_store(ovec[3], &out4[base + 3 * stride]);
    } else {
        for (int i = base; i < n4; i += stride) {
            f32x4 xv = x4[i];
            const int c4 = i & (NCHAN / 4 - 1);
            f32x4 dv = ((const f32x4*)sdiv)[c4];
            f32x4 mv = ((const f32x4*)smul)[c4];
            f32x4 o;
#pragma unroll
            for (int j = 0; j < 4; ++j) o[j] = quant_exact(xv[j], dv[j], mv[j], qlut);
            __builtin_nontemporal_store(o, &out4[i]);
        }
    }
}

extern "C" void kernel_launch(void* const* d_in, const int* in_sizes, int n_in,
                              void* d_out, int out_size, void* d_ws, size_t ws_size,
                              hipStream_t stream) {
    const float* x       = (const float*)d_in[0];
    const float* scale   = (const float*)d_in[1];
    const float* centers = (const float*)d_in[2];
    float* out           = (float*)d_out;

    const int n  = in_sizes[0];
    const int n4 = n / 4;

    const int block = 256;
    // 4 float4s per thread; n4 = 2^21 -> grid = 2048 = 8 blocks/CU (all resident)
    int grid = (n4 + block * 4 - 1) / (block * 4);
    if (grid > 2048) grid = 2048;

    lut_fakequant_kernel<<<grid, block, 0, stream>>>(x, scale, centers, out, n4);
}

// Round 9
// 14.628 us; speedup vs baseline: 1.0533x; 1.0533x over previous
//
#include <hip/hip_runtime.h>

#define EPSF 1e-8f
#define NCENT 16
#define NCHAN 128
#define NCELL 511          // cell = floor(2t)+256 for t in [-128,127] -> [0,510]
#define TOL   2e-4f        // boundary-nearness guard in t2-units (err bound 4.6e-5, 4x margin)
#define TOLT  1e-4f        // definite-saturation guard in t-units (err bound 2.8e-5)

typedef float f32x4 __attribute__((ext_vector_type(4)));

// sc1-only store: device-scope (no per-XCD L2 allocate -> avoids R6's L2 thrash)
// but NO nt bit -> memory-side Infinity Cache may allocate. Steady-state graph
// replays then rewrite the same resident L3 lines instead of streaming to HBM.
__device__ __forceinline__ void store_sc1(f32x4* p, f32x4 v) {
    asm volatile("global_store_dwordx4 %0, %1, off sc1"
                 :: "v"(p), "v"(v) : "memory");
}

// Exact reference argmin: first-index tie-break (strict <), centers pre-rounded.
__device__ __forceinline__ float nearest_center(float t, const float* c) {
    float best = fabsf(t - c[0]);
    float q = c[0];
#pragma unroll
    for (int k = 1; k < NCENT; ++k) {
        float d = fabsf(t - c[k]);
        bool lt = d < best;
        best = lt ? d : best;
        q = lt ? c[k] : q;
    }
    return q;
}

// Bit-exact slow path: full IEEE divide (verified absmax==0 in R2-R8).
__device__ __forceinline__ float quant_exact(float xin, float sdv, float sml,
                                             const float* qlut) {
    float t = xin / sdv;                       // sdv = (scale+eps)/128, pow2-exact fold
    t = fminf(fmaxf(t, -128.0f), 127.0f);
    float t2 = t + t;
    float f = floorf(t2);
    int cell = (int)f + 256;
    int idx = (t2 == f) ? (cell + 512) : cell;
    return qlut[idx] * sml;
}

// Fast path: reciprocal multiply + exactness guard. Sets `slow` when the
// approx t2 is too close to an integer to trust cell/boundary assignment.
__device__ __forceinline__ float quant_fast(float xin, float rrec, float sml,
                                            const float* qlut, bool& slow) {
    float ta = xin * rrec;                     // |t2a - t2exact| <= ~4.6e-5
    float t = fminf(fmaxf(ta, -128.0f), 127.0f);
    float t2 = t + t;
    float f = floorf(t2);
    float d = t2 - f;                          // exact subtraction, in [0,1)
    int cell = (int)f + 256;
    int idx = (d == 0.0f) ? (cell + 512) : cell;
    bool near = (d < TOL) | (d > 1.0f - TOL);
    // definitely saturated: exact t also clips -> boundary LUT correct, keep fast
    bool defsat = (ta > 127.0f + TOLT) | (ta < -128.0f - TOLT);
    slow = near & !defsat;
    return qlut[idx] * sml;
}

__global__ __launch_bounds__(256) void lut_fakequant_kernel(
    const float* __restrict__ x,
    const float* __restrict__ scale,
    const float* __restrict__ centers_g,
    float* __restrict__ out,
    int n4)
{
    __shared__ float srec[NCHAN];        // fl(1 / ((scale+eps)/128))
    __shared__ float sdiv[NCHAN];        // (scale+eps)/128  (exact pow2 scaling)
    __shared__ float smul[NCHAN];        // scale/128        (exact pow2 scaling)
    __shared__ float qlut[NCELL + 512];  // [0..510]=interior, [512..1022]=boundary

    const int base = blockIdx.x * blockDim.x + threadIdx.x;
    const int stride = gridDim.x * blockDim.x;
    const bool fastpath = (base + 3 * stride < n4);

    const f32x4* __restrict__ x4 = (const f32x4*)x;
    f32x4* __restrict__ out4 = (f32x4*)out;

    // Issue the x loads FIRST (cached; latency covers the whole prologue, R7: -1.65 us).
    f32x4 v0, v1, v2, v3;
    if (fastpath) {
        v0 = x4[base];
        v1 = x4[base + stride];
        v2 = x4[base + 2 * stride];
        v3 = x4[base + 3 * stride];
    }

    // Prologue: scale/centers loads + LUT build, overlapped with x loads.
    if (threadIdx.x < NCHAN) {
        float s = scale[threadIdx.x];
        float dv = (s + EPSF) * 0.0078125f;
        sdiv[threadIdx.x] = dv;
        srec[threadIdx.x] = 1.0f / dv;
        smul[threadIdx.x] = s * 0.0078125f;
    }

    // Rounded codebook (uniform addr). jnp.round == round-half-even == rintf.
    float c[NCENT];
#pragma unroll
    for (int k = 0; k < NCENT; ++k) c[k] = rintf(centers_g[k]);

    // Piecewise-constant LUT built with the exact reference argmin.
    for (int u = threadIdx.x; u < NCELL; u += blockDim.x) {
        float tb = (float)(u - 256) * 0.5f;
        qlut[u]       = nearest_center(tb + 0.25f, c);  // interior of cell
        qlut[u + 512] = nearest_center(tb, c);          // exact-boundary (tie-break)
    }
    __syncthreads();

    if (fastpath) {
        const int c4 = base & (NCHAN / 4 - 1);   // stride%32==0 -> shared channel slot
        f32x4 rv = ((const f32x4*)srec)[c4];
        f32x4 mv = ((const f32x4*)smul)[c4];

        f32x4 vin[4] = {v0, v1, v2, v3};
        f32x4 ovec[4];
#pragma unroll
        for (int g = 0; g < 4; ++g) {
            bool s0, s1, s2, s3;
            f32x4 o;
            o[0] = quant_fast(vin[g][0], rv[0], mv[0], qlut, s0);
            o[1] = quant_fast(vin[g][1], rv[1], mv[1], qlut, s1);
            o[2] = quant_fast(vin[g][2], rv[2], mv[2], qlut, s2);
            o[3] = quant_fast(vin[g][3], rv[3], mv[3], qlut, s3);
            if (__builtin_expect(s0 | s1 | s2 | s3, 0)) {   // rare divergent redo
                f32x4 dv = ((const f32x4*)sdiv)[c4];
                if (s0) o[0] = quant_exact(vin[g][0], dv[0], mv[0], qlut);
                if (s1) o[1] = quant_exact(vin[g][1], dv[1], mv[1], qlut);
                if (s2) o[2] = quant_exact(vin[g][2], dv[2], mv[2], qlut);
                if (s3) o[3] = quant_exact(vin[g][3], dv[3], mv[3], qlut);
            }
            ovec[g] = o;
        }

        store_sc1(&out4[base],              ovec[0]);
        store_sc1(&out4[base + stride],     ovec[1]);
        store_sc1(&out4[base + 2 * stride], ovec[2]);
        store_sc1(&out4[base + 3 * stride], ovec[3]);
    } else {
        for (int i = base; i < n4; i += stride) {
            f32x4 xv = x4[i];
            const int c4 = i & (NCHAN / 4 - 1);
            f32x4 dv = ((const f32x4*)sdiv)[c4];
            f32x4 mv = ((const f32x4*)smul)[c4];
            f32x4 o;
#pragma unroll
            for (int j = 0; j < 4; ++j) o[j] = quant_exact(xv[j], dv[j], mv[j], qlut);
            store_sc1(&out4[i], o);
        }
    }
}

extern "C" void kernel_launch(void* const* d_in, const int* in_sizes, int n_in,
                              void* d_out, int out_size, void* d_ws, size_t ws_size,
                              hipStream_t stream) {
    const float* x       = (const float*)d_in[0];
    const float* scale   = (const float*)d_in[1];
    const float* centers = (const float*)d_in[2];
    float* out           = (float*)d_out;

    const int n  = in_sizes[0];
    const int n4 = n / 4;

    const int block = 256;
    // 4 float4s per thread; n4 = 2^21 -> grid = 2048 = 8 blocks/CU (all resident)
    int grid = (n4 + block * 4 - 1) / (block * 4);
    if (grid > 2048) grid = 2048;

    lut_fakequant_kernel<<<grid, block, 0, stream>>>(x, scale, centers, out, n4);
}

// Round 10
// 13.969 us; speedup vs baseline: 1.1030x; 1.0472x over previous
//
#include <hip/hip_runtime.h>

#define EPSF 1e-8f
#define NCENT 16
#define NCHAN 128
#define NCELL 511          // cell = floor(2t)+256 for t in [-128,127] -> [0,510]
#define TOL   2e-4f        // boundary-nearness guard in t2-units (err bound 4.6e-5, 4x margin)
#define TOLT  1e-4f        // definite-saturation guard in t-units (err bound 2.8e-5)
#define NB    8            // float4s per thread (was 4): deeper MLP, half the blocks

typedef float f32x4 __attribute__((ext_vector_type(4)));

// sc1-only store: device-scope, no per-XCD L2 allocate (R6: cached stores +2.2us),
// marginally best measured vs nt (R9).
__device__ __forceinline__ void store_sc1(f32x4* p, f32x4 v) {
    asm volatile("global_store_dwordx4 %0, %1, off sc1"
                 :: "v"(p), "v"(v) : "memory");
}

// Exact reference argmin: first-index tie-break (strict <), centers pre-rounded.
__device__ __forceinline__ float nearest_center(float t, const float* c) {
    float best = fabsf(t - c[0]);
    float q = c[0];
#pragma unroll
    for (int k = 1; k < NCENT; ++k) {
        float d = fabsf(t - c[k]);
        bool lt = d < best;
        best = lt ? d : best;
        q = lt ? c[k] : q;
    }
    return q;
}

// Bit-exact slow path: full IEEE divide (verified absmax==0 in R2-R9).
__device__ __forceinline__ float quant_exact(float xin, float sdv, float sml,
                                             const float* qlut) {
    float t = xin / sdv;                       // sdv = (scale+eps)/128, pow2-exact fold
    t = fminf(fmaxf(t, -128.0f), 127.0f);
    float t2 = t + t;
    float f = floorf(t2);
    int cell = (int)f + 256;
    int idx = (t2 == f) ? (cell + 512) : cell;
    return qlut[idx] * sml;
}

// Fast path: reciprocal multiply + exactness guard. Sets `slow` when the
// approx t2 is too close to an integer to trust cell/boundary assignment.
__device__ __forceinline__ float quant_fast(float xin, float rrec, float sml,
                                            const float* qlut, bool& slow) {
    float ta = xin * rrec;                     // |t2a - t2exact| <= ~4.6e-5
    float t = fminf(fmaxf(ta, -128.0f), 127.0f);
    float t2 = t + t;
    float f = floorf(t2);
    float d = t2 - f;                          // exact subtraction, in [0,1)
    int cell = (int)f + 256;
    int idx = (d == 0.0f) ? (cell + 512) : cell;
    bool near = (d < TOL) | (d > 1.0f - TOL);
    // definitely saturated: exact t also clips -> boundary LUT correct, keep fast
    bool defsat = (ta > 127.0f + TOLT) | (ta < -128.0f - TOLT);
    slow = near & !defsat;
    return qlut[idx] * sml;
}

__global__ __launch_bounds__(256) void lut_fakequant_kernel(
    const float* __restrict__ x,
    const float* __restrict__ scale,
    const float* __restrict__ centers_g,
    float* __restrict__ out,
    int n4)
{
    __shared__ float srec[NCHAN];        // fl(1 / ((scale+eps)/128))
    __shared__ float sdiv[NCHAN];        // (scale+eps)/128  (exact pow2 scaling)
    __shared__ float smul[NCHAN];        // scale/128        (exact pow2 scaling)
    __shared__ float qlut[NCELL + 512];  // [0..510]=interior, [512..1022]=boundary

    const int base = blockIdx.x * blockDim.x + threadIdx.x;
    const int stride = gridDim.x * blockDim.x;
    const bool fastpath = (base + (NB - 1) * stride < n4);

    const f32x4* __restrict__ x4 = (const f32x4*)x;
    f32x4* __restrict__ out4 = (f32x4*)out;

    // Issue ALL NB x loads FIRST (cached; x is L3-resident across replays, R5).
    // 8 independent 16B loads/thread: latency covers the prologue (R7) AND
    // gives in-thread pipelining -- compute of group g overlaps returns of g+1..7.
    f32x4 vin[NB];
    if (fastpath) {
#pragma unroll
        for (int g = 0; g < NB; ++g) vin[g] = x4[base + g * stride];
    }

    // Prologue: scale/centers loads + LUT build, overlapped with x loads.
    if (threadIdx.x < NCHAN) {
        float s = scale[threadIdx.x];
        float dv = (s + EPSF) * 0.0078125f;
        sdiv[threadIdx.x] = dv;
        srec[threadIdx.x] = 1.0f / dv;
        smul[threadIdx.x] = s * 0.0078125f;
    }

    // Rounded codebook (uniform addr). jnp.round == round-half-even == rintf.
    float c[NCENT];
#pragma unroll
    for (int k = 0; k < NCENT; ++k) c[k] = rintf(centers_g[k]);

    // Piecewise-constant LUT built with the exact reference argmin.
    for (int u = threadIdx.x; u < NCELL; u += blockDim.x) {
        float tb = (float)(u - 256) * 0.5f;
        qlut[u]       = nearest_center(tb + 0.25f, c);  // interior of cell
        qlut[u + 512] = nearest_center(tb, c);          // exact-boundary (tie-break)
    }
    __syncthreads();

    if (fastpath) {
        const int c4 = base & (NCHAN / 4 - 1);   // stride%32==0 -> shared channel slot
        f32x4 rv = ((const f32x4*)srec)[c4];
        f32x4 mv = ((const f32x4*)smul)[c4];

#pragma unroll
        for (int g = 0; g < NB; ++g) {
            bool s0, s1, s2, s3;
            f32x4 o;
            o[0] = quant_fast(vin[g][0], rv[0], mv[0], qlut, s0);
            o[1] = quant_fast(vin[g][1], rv[1], mv[1], qlut, s1);
            o[2] = quant_fast(vin[g][2], rv[2], mv[2], qlut, s2);
            o[3] = quant_fast(vin[g][3], rv[3], mv[3], qlut, s3);
            if (__builtin_expect(s0 | s1 | s2 | s3, 0)) {   // rare divergent redo
                f32x4 dv = ((const f32x4*)sdiv)[c4];
                if (s0) o[0] = quant_exact(vin[g][0], dv[0], mv[0], qlut);
                if (s1) o[1] = quant_exact(vin[g][1], dv[1], mv[1], qlut);
                if (s2) o[2] = quant_exact(vin[g][2], dv[2], mv[2], qlut);
                if (s3) o[3] = quant_exact(vin[g][3], dv[3], mv[3], qlut);
            }
            // Store as soon as computed: interleaves with remaining compute.
            store_sc1(&out4[base + g * stride], o);
        }
    } else {
        for (int i = base; i < n4; i += stride) {
            f32x4 xv = x4[i];
            const int c4 = i & (NCHAN / 4 - 1);
            f32x4 dv = ((const f32x4*)sdiv)[c4];
            f32x4 mv = ((const f32x4*)smul)[c4];
            f32x4 o;
#pragma unroll
            for (int j = 0; j < 4; ++j) o[j] = quant_exact(xv[j], dv[j], mv[j], qlut);
            store_sc1(&out4[i], o);
        }
    }
}

extern "C" void kernel_launch(void* const* d_in, const int* in_sizes, int n_in,
                              void* d_out, int out_size, void* d_ws, size_t ws_size,
                              hipStream_t stream) {
    const float* x       = (const float*)d_in[0];
    const float* scale   = (const float*)d_in[1];
    const float* centers = (const float*)d_in[2];
    float* out           = (float*)d_out;

    const int n  = in_sizes[0];
    const int n4 = n / 4;

    const int block = 256;
    // NB float4s per thread; n4 = 2^21 -> grid = 1024 = 4 blocks/CU (all resident)
    int grid = (n4 + block * NB - 1) / (block * NB);
    if (grid > 2048) grid = 2048;

    lut_fakequant_kernel<<<grid, block, 0, stream>>>(x, scale, centers, out, n4);
}

// Round 11
// 13.861 us; speedup vs baseline: 1.1116x; 1.0078x over previous
//
#include <hip/hip_runtime.h>

#define EPSF 1e-8f
#define NCENT 16
#define NCHAN 128
#define NCELL 511          // cell = floor(2t)+256 for t in [-128,127] -> [0,510]
#define TOL   2e-4f        // boundary-nearness guard in t2-units (err bound 4.6e-5, 4x margin)
#define TOLT  1e-4f        // definite-saturation guard in t-units (err bound 2.8e-5)
#define NB    16           // float4s per thread (R10: 8 -> -0.66us). Same 4-wave/SIMD
                           // VGPR band (~105 < 128), 2x loads in flight per wave.

typedef float f32x4 __attribute__((ext_vector_type(4)));

// sc1-only store: device-scope, no per-XCD L2 allocate (R6: cached stores +2.2us),
// marginally best measured vs nt (R9).
__device__ __forceinline__ void store_sc1(f32x4* p, f32x4 v) {
    asm volatile("global_store_dwordx4 %0, %1, off sc1"
                 :: "v"(p), "v"(v) : "memory");
}

// Exact reference argmin: first-index tie-break (strict <), centers pre-rounded.
__device__ __forceinline__ float nearest_center(float t, const float* c) {
    float best = fabsf(t - c[0]);
    float q = c[0];
#pragma unroll
    for (int k = 1; k < NCENT; ++k) {
        float d = fabsf(t - c[k]);
        bool lt = d < best;
        best = lt ? d : best;
        q = lt ? c[k] : q;
    }
    return q;
}

// Bit-exact slow path: full IEEE divide (verified absmax==0 in R2-R10).
__device__ __forceinline__ float quant_exact(float xin, float sdv, float sml,
                                             const float* qlut) {
    float t = xin / sdv;                       // sdv = (scale+eps)/128, pow2-exact fold
    t = fminf(fmaxf(t, -128.0f), 127.0f);
    float t2 = t + t;
    float f = floorf(t2);
    int cell = (int)f + 256;
    int idx = (t2 == f) ? (cell + 512) : cell;
    return qlut[idx] * sml;
}

// Fast path: reciprocal multiply + exactness guard. Sets `slow` when the
// approx t2 is too close to an integer to trust cell/boundary assignment.
__device__ __forceinline__ float quant_fast(float xin, float rrec, float sml,
                                            const float* qlut, bool& slow) {
    float ta = xin * rrec;                     // |t2a - t2exact| <= ~4.6e-5
    float t = fminf(fmaxf(ta, -128.0f), 127.0f);
    float t2 = t + t;
    float f = floorf(t2);
    float d = t2 - f;                          // exact subtraction, in [0,1)
    int cell = (int)f + 256;
    int idx = (d == 0.0f) ? (cell + 512) : cell;
    bool near = (d < TOL) | (d > 1.0f - TOL);
    // definitely saturated: exact t also clips -> boundary LUT correct, keep fast
    bool defsat = (ta > 127.0f + TOLT) | (ta < -128.0f - TOLT);
    slow = near & !defsat;
    return qlut[idx] * sml;
}

__global__ __launch_bounds__(256) void lut_fakequant_kernel(
    const float* __restrict__ x,
    const float* __restrict__ scale,
    const float* __restrict__ centers_g,
    float* __restrict__ out,
    int n4)
{
    __shared__ float srec[NCHAN];        // fl(1 / ((scale+eps)/128))
    __shared__ float sdiv[NCHAN];        // (scale+eps)/128  (exact pow2 scaling)
    __shared__ float smul[NCHAN];        // scale/128        (exact pow2 scaling)
    __shared__ float qlut[NCELL + 512];  // [0..510]=interior, [512..1022]=boundary

    const int base = blockIdx.x * blockDim.x + threadIdx.x;
    const int stride = gridDim.x * blockDim.x;
    const bool fastpath = (base + (NB - 1) * stride < n4);

    const f32x4* __restrict__ x4 = (const f32x4*)x;
    f32x4* __restrict__ out4 = (f32x4*)out;

    // Issue ALL NB x loads FIRST (cached; x is L3-resident across replays, R5).
    // 16 independent 16B loads/thread: latency covers the prologue (R7) AND
    // deep in-thread pipelining (R10 lever).
    f32x4 vin[NB];
    if (fastpath) {
#pragma unroll
        for (int g = 0; g < NB; ++g) vin[g] = x4[base + g * stride];
    }

    // Prologue: scale/centers loads + LUT build, overlapped with x loads.
    if (threadIdx.x < NCHAN) {
        float s = scale[threadIdx.x];
        float dv = (s + EPSF) * 0.0078125f;
        sdiv[threadIdx.x] = dv;
        srec[threadIdx.x] = 1.0f / dv;
        smul[threadIdx.x] = s * 0.0078125f;
    }

    // Rounded codebook (uniform addr). jnp.round == round-half-even == rintf.
    float c[NCENT];
#pragma unroll
    for (int k = 0; k < NCENT; ++k) c[k] = rintf(centers_g[k]);

    // Piecewise-constant LUT built with the exact reference argmin.
    for (int u = threadIdx.x; u < NCELL; u += blockDim.x) {
        float tb = (float)(u - 256) * 0.5f;
        qlut[u]       = nearest_center(tb + 0.25f, c);  // interior of cell
        qlut[u + 512] = nearest_center(tb, c);          // exact-boundary (tie-break)
    }
    __syncthreads();

    if (fastpath) {
        const int c4 = base & (NCHAN / 4 - 1);   // stride%32==0 -> shared channel slot
        f32x4 rv = ((const f32x4*)srec)[c4];
        f32x4 mv = ((const f32x4*)smul)[c4];

#pragma unroll
        for (int g = 0; g < NB; ++g) {
            bool s0, s1, s2, s3;
            f32x4 o;
            o[0] = quant_fast(vin[g][0], rv[0], mv[0], qlut, s0);
            o[1] = quant_fast(vin[g][1], rv[1], mv[1], qlut, s1);
            o[2] = quant_fast(vin[g][2], rv[2], mv[2], qlut, s2);
            o[3] = quant_fast(vin[g][3], rv[3], mv[3], qlut, s3);
            if (__builtin_expect(s0 | s1 | s2 | s3, 0)) {   // rare divergent redo
                f32x4 dv = ((const f32x4*)sdiv)[c4];
                if (s0) o[0] = quant_exact(vin[g][0], dv[0], mv[0], qlut);
                if (s1) o[1] = quant_exact(vin[g][1], dv[1], mv[1], qlut);
                if (s2) o[2] = quant_exact(vin[g][2], dv[2], mv[2], qlut);
                if (s3) o[3] = quant_exact(vin[g][3], dv[3], mv[3], qlut);
            }
            // Store as soon as computed: frees o, interleaves with compute.
            store_sc1(&out4[base + g * stride], o);
        }
    } else {
        for (int i = base; i < n4; i += stride) {
            f32x4 xv = x4[i];
            const int c4 = i & (NCHAN / 4 - 1);
            f32x4 dv = ((const f32x4*)sdiv)[c4];
            f32x4 mv = ((const f32x4*)smul)[c4];
            f32x4 o;
#pragma unroll
            for (int j = 0; j < 4; ++j) o[j] = quant_exact(xv[j], dv[j], mv[j], qlut);
            store_sc1(&out4[i], o);
        }
    }
}

extern "C" void kernel_launch(void* const* d_in, const int* in_sizes, int n_in,
                              void* d_out, int out_size, void* d_ws, size_t ws_size,
                              hipStream_t stream) {
    const float* x       = (const float*)d_in[0];
    const float* scale   = (const float*)d_in[1];
    const float* centers = (const float*)d_in[2];
    float* out           = (float*)d_out;

    const int n  = in_sizes[0];
    const int n4 = n / 4;

    const int block = 256;
    // NB float4s per thread; n4 = 2^21 -> grid = 512 = 2 blocks/CU (all resident)
    int grid = (n4 + block * NB - 1) / (block * NB);
    if (grid > 2048) grid = 2048;

    lut_fakequant_kernel<<<grid, block, 0, stream>>>(x, scale, centers, out, n4);
}